// Round 17
// baseline (59.878 us; speedup 1.0000x reference)
//
#include <hip/hip_runtime.h>

#define FG 15
#define NPROP 512
#define NCLS 16
#define NCI 30   // B*FG
#define SCORE_T 0.05f
#define NMS_T 0.5f
#define DETS 100
#define STRIPES 8
#define NWAVES 8
#define WCAP 512  // per-wave pair staging

typedef unsigned long long u64;
typedef unsigned int u32;

__device__ __forceinline__ unsigned sortable_f32(float f) {
  unsigned u = __float_as_uint(f);
  return u ^ ((u >> 31) ? 0xFFFFFFFFu : 0x80000000u);
}

// ---------------- register Sutherland-Hodgman (fast-math; IoU slack >> rounding) --------
#define CLIP_EMIT(V, VALIDEXPR, CX, CY, NX, NY)                                \
  {                                                                            \
    bool valid = (VALIDEXPR);                                                  \
    float cx = (CX), cy = (CY), nx = (NX), ny = (NY);                          \
    float sc = ex * (cy - p1y) - ey * (cx - p1x);                              \
    float sn = ex * (ny - p1y) - ey * (nx - p1x);                              \
    bool ic = sc >= 0.f, inn = sn >= 0.f;                                      \
    float den = sc - sn;                                                       \
    float dsel = (fabsf(den) > 1e-8f) ? den : 1.f;                             \
    float tt = sc * __builtin_amdgcn_rcpf(dsel);                               \
    float qx = cx + tt * (nx - cx);                                            \
    float qy = cy + tt * (ny - cy);                                            \
    bool fC = valid && ic;                                                     \
    bool fI = valid && (ic != inn);                                            \
    _Pragma("unroll") for (int o = 0; o < 8; ++o) if (o <= 2 * (V)) {          \
      bool wr = fC && (m == o);                                                \
      ox[o] = wr ? cx : ox[o];                                                 \
      oy[o] = wr ? cy : oy[o];                                                 \
    }                                                                          \
    m += fC ? 1 : 0;                                                           \
    _Pragma("unroll") for (int o = 0; o < 8; ++o) if (o <= 2 * (V) + 1) {      \
      bool wr = fI && (m == o);                                                \
      ox[o] = wr ? qx : ox[o];                                                 \
      oy[o] = wr ? qy : oy[o];                                                 \
    }                                                                          \
    m += fI ? 1 : 0;                                                           \
  }

__device__ __forceinline__ float inter_area_fast(const float (&Ax)[4], const float (&Ay)[4],
                                                 const float (&Bx)[4], const float (&By)[4]) {
  float inx[8], iny[8];
  int n = 4;
#pragma unroll
  for (int v = 0; v < 4; ++v) {
    inx[v] = Ax[v]; iny[v] = Ay[v];
    inx[v + 4] = 0.f; iny[v + 4] = 0.f;
  }
#pragma unroll
  for (int e = 0; e < 4; ++e) {
    int e2 = (e + 1) & 3;
    float p1x = Bx[e], p1y = By[e];
    float ex = Bx[e2] - p1x, ey = By[e2] - p1y;
    float ox[8], oy[8];
    int m = 0;
#pragma unroll
    for (int o = 0; o < 8; ++o) { ox[o] = 0.f; oy[o] = 0.f; }
    if (e == 0) {  // n == 4 statically
#pragma unroll
      for (int v = 0; v < 4; ++v) {
        CLIP_EMIT(v, true, inx[v], iny[v], inx[(v + 1) & 3], iny[(v + 1) & 3]);
      }
    } else {
#pragma unroll
      for (int v = 0; v < 8; ++v) {
        bool wrap = (v + 1 >= n);
        CLIP_EMIT(v, v < n, inx[v], iny[v],
                  wrap ? inx[0] : inx[(v + 1) & 7],
                  wrap ? iny[0] : iny[(v + 1) & 7]);
      }
    }
    n = (m < 8) ? m : 8;
#pragma unroll
    for (int o = 0; o < 8; ++o) { inx[o] = ox[o]; iny[o] = oy[o]; }
  }
  float s = 0.f;
#pragma unroll
  for (int v = 0; v < 8; ++v) {
    bool valid = v < n;
    bool wrap = (v + 1 >= n);
    float axx = inx[v], ayy = iny[v];
    float bxx = wrap ? inx[0] : inx[(v + 1) & 7];
    float byy = wrap ? iny[0] : iny[(v + 1) & 7];
    float cr = axx * byy - bxx * ayy;
    s += valid ? cr : 0.f;
  }
  float area = 0.5f * fabsf(s);
  return (n >= 3) ? area : 0.f;
}

// ---------------- kernel 1: decode + compacted rank-sort + AABB filter + clip ------------
// R16 verbatim: block (ci,s) owns mask rows i == s (mod 8). Per-wave filter
// staging (no atomics), LDS-assembled mask written with plain coalesced
// stores. float4 logits loads; fast __sinf/__cosf corners (decisions
// slack-protected); output boxes/scores bit-exact.
__global__ void __launch_bounds__(512) k_pipe(
    const float* __restrict__ logits, const float* __restrict__ regr,
    const float* __restrict__ prop,
    float* __restrict__ ssort, float* __restrict__ bsort,
    u64* __restrict__ mask) {
  int ci = blockIdx.x;
  int s = blockIdx.y;
  int b = ci / FG, c = ci - b * FG + 1;  // class 1..15
  int tid = threadIdx.x, lane = tid & 63, wv = tid >> 6;

  __shared__ __align__(16) u64 key2[NPROP + 8];     // compacted valid keys + pad
  __shared__ int rmap[NPROP];                       // orig tid -> rank
  __shared__ int cnt[NWAVES];
  __shared__ __align__(16) float crn[NPROP][8];     // 16 KB sorted corners
  __shared__ float4 aabb[NPROP];                    //  8 KB
  __shared__ float areaL[NPROP];                    //  2 KB
  __shared__ u32 stage[NWAVES][WCAP];               // 16 KB per-wave regions
  __shared__ int wcnts[NWAVES];
  __shared__ u64 lmask2[NPROP];                     //  4 KB own-rows mask

  lmask2[tid] = 0ull;

  // ---- decode + softmax (bit-identical to reference path) ----
  float sc, bb[5];
  u64 k;
  {
#pragma clang fp contract(off)
    int g = b * NPROP + tid;
    const float4* lg4 = (const float4*)(logits + g * NCLS);  // 64B-aligned
    float l[NCLS];
#pragma unroll
    for (int q4 = 0; q4 < 4; ++q4) {
      float4 v = lg4[q4];
      l[q4 * 4 + 0] = v.x; l[q4 * 4 + 1] = v.y;
      l[q4 * 4 + 2] = v.z; l[q4 * 4 + 3] = v.w;
    }
    float mx = -INFINITY;
#pragma unroll
    for (int q = 0; q < NCLS; ++q) mx = fmaxf(mx, l[q]);
    float sum = 0.f, ec = 0.f;
#pragma unroll
    for (int q = 0; q < NCLS; ++q) {
      float e = expf(l[q] - mx);
      sum += e;
      if (q == c) ec = e;
    }
    sc = ec / sum;
    const float* pb = prop + g * 5;
    float xc = pb[0], yc = pb[1], w = pb[2], h = pb[3], a = pb[4];
    const float* r = regr + g * 80 + c * 5;
    float dx = r[0] / 10.0f;
    float dy = r[1] / 10.0f;
    float dw = fminf(r[2] / 5.0f, 4.135166556742356f);
    float dh = fminf(r[3] / 5.0f, 4.135166556742356f);
    float da = r[4] / 10.0f;
    bb[0] = dx * w + xc;
    bb[1] = dy * h + yc;
    bb[2] = expf(dw) * w;
    bb[3] = expf(dh) * h;
    bb[4] = da * 57.29577951308232f + a;
    float m = (sc > SCORE_T) ? sc : -INFINITY;
    k = ((u64)(~sortable_f32(m)) << 32) | (u32)tid;  // asc key = desc score, asc idx
  }
  bool val = sc > SCORE_T;
  u64 bal = __ballot(val);
  if (lane == 0) cnt[wv] = (int)__popcll(bal);
  __syncthreads();
  int base = 0, V = 0;
#pragma unroll
  for (int w = 0; w < NWAVES; ++w) {
    int cw = cnt[w];
    base += (w < wv) ? cw : 0;
    V += cw;
  }
  if (val) key2[base + (int)__popcll(bal & ((1ull << lane) - 1ull))] = k;
  int Vpad = (V + 7) & ~7;
  if (tid < Vpad - V) key2[V + tid] = ~0ull;  // sentinel: > every real key
  __syncthreads();

  // ---- rank over valid-only keys (strictly distinct => bijective) ----
  if (tid < V) {
    u64 myk = key2[tid];
    int rank = 0;
    const ulonglong2* k2 = (const ulonglong2*)key2;
#pragma unroll 4
    for (int m = 0; m < Vpad / 2; ++m) {
      ulonglong2 kk = k2[m];  // ds_read_b128 broadcast
      rank += (kk.x < myk) ? 1 : 0;
      rank += (kk.y < myk) ? 1 : 0;
    }
    rmap[(int)(myk & 0xFFFFFFFFull)] = rank;
    if (s == 0) {  // bit-exact score recovery from the key
      u32 so = ~(u32)(myk >> 32);
      ssort[ci * NPROP + rank] = __uint_as_float(so ^ 0x80000000u);
    }
  }
  if (tid >= V && s == 0) ssort[ci * NPROP + tid] = -INFINITY;
  __syncthreads();

  // ---- scatter geometry by rank (fast trig; decisions slack-protected) ----
  if (val) {
    int r = rmap[tid];
    {
      float t = bb[4] * 0.017453292519943295f;
      float cs = __cosf(t), sn = __sinf(t);
      float hw = bb[2] * 0.5f, hh = bb[3] * 0.5f;
      float lx[4] = {-hw, hw, hw, -hw};
      float ly[4] = {-hh, -hh, hh, hh};
      float X[4], Y[4];
#pragma unroll
      for (int q = 0; q < 4; ++q) {
        X[q] = bb[0] + lx[q] * cs - ly[q] * sn;
        Y[q] = bb[1] + lx[q] * sn + ly[q] * cs;
      }
#pragma unroll
      for (int q = 0; q < 4; ++q) { crn[r][q] = X[q]; crn[r][4 + q] = Y[q]; }
      float xmn = fminf(fminf(X[0], X[1]), fminf(X[2], X[3]));
      float xmx = fmaxf(fmaxf(X[0], X[1]), fmaxf(X[2], X[3]));
      float ymn = fminf(fminf(Y[0], Y[1]), fminf(Y[2], Y[3]));
      float ymx = fmaxf(fmaxf(Y[0], Y[1]), fmaxf(Y[2], Y[3]));
      aabb[r] = make_float4(xmn, ymn, xmx, ymx);
      areaL[r] = bb[2] * bb[3];
      if (s == 0) {
        float* dst = bsort + ((size_t)ci * NPROP + r) * 5;
#pragma unroll
        for (int q = 0; q < 5; ++q) dst[q] = bb[q];
      }
    }
  }
  __syncthreads();

  // ---- phase 1: per-wave AABB filter, ballot-prefix staging (no atomics) ----
  // IoU>0.5 needs inter > (A+B)/3 and inter <= AABB-overlap-area, so require
  // AABBinter > 0.33*(A+B) (1% slack >> fp rounding; AABB-disjoint => inter==0).
  {
    int nch = (V + 63) >> 6;
    int wcnt = 0;
    for (int t = wv;; t += NWAVES) {
      int i = s + STRIPES * t;  // rows i == s (mod 8), round-robin over waves
      if (i >= V) break;
      float4 ai = aabb[i];
      float Ai = areaL[i];
      for (int ch = i >> 6; ch < nch; ++ch) {
        int j = (ch << 6) | lane;
        bool pass = false;
        if (j > i && j < V) {
          float4 aj = aabb[j];
          float ix = fminf(ai.z, aj.z) - fmaxf(ai.x, aj.x);
          float iy = fminf(ai.w, aj.w) - fmaxf(ai.y, aj.y);
          float ov = fmaxf(ix, 0.f) * fmaxf(iy, 0.f);  // >= exact quad intersection
          pass = ov > 0.33f * (Ai + areaL[j]);
        }
        u64 bal2 = __ballot(pass);
        if (pass) {
          int pos = wcnt + (int)__popcll(bal2 & ((1ull << lane) - 1ull));
          if (pos < WCAP) stage[wv][pos] = ((u32)i << 9) | (u32)j;
        }
        wcnt += (int)__popcll(bal2);
      }
    }
    if (lane == 0) wcnts[wv] = wcnt < WCAP ? wcnt : WCAP;
  }
  __syncthreads();

  // ---- phase 2: clip staged pairs (balanced over all 512 threads) ----
  {
    int c0 = wcnts[0], c1 = wcnts[1], c2 = wcnts[2], c3 = wcnts[3];
    int c4 = wcnts[4], c5 = wcnts[5], c6 = wcnts[6], c7 = wcnts[7];
    int p1 = c0, p2 = p1 + c1, p3 = p2 + c2, p4 = p3 + c3;
    int p5 = p4 + c4, p6 = p5 + c5, p7 = p6 + c6;
    int total = p7 + c7;
    for (int p = tid; p < total; p += 512) {
      int r = (p >= p1) + (p >= p2) + (p >= p3) + (p >= p4) +
              (p >= p5) + (p >= p6) + (p >= p7);
      u32 w = 0;
      switch (r) {  // static region indexing
        case 0: w = stage[0][p]; break;
        case 1: w = stage[1][p - p1]; break;
        case 2: w = stage[2][p - p2]; break;
        case 3: w = stage[3][p - p3]; break;
        case 4: w = stage[4][p - p4]; break;
        case 5: w = stage[5][p - p5]; break;
        case 6: w = stage[6][p - p6]; break;
        default: w = stage[7][p - p7]; break;
      }
      int i = w >> 9, j = w & 511;
      float4 a0 = *(const float4*)&crn[i][0];
      float4 a1 = *(const float4*)&crn[i][4];
      float4 b0 = *(const float4*)&crn[j][0];
      float4 b1 = *(const float4*)&crn[j][4];
      float Ax[4] = {a0.x, a0.y, a0.z, a0.w};
      float Ay[4] = {a1.x, a1.y, a1.z, a1.w};
      float Bx[4] = {b0.x, b0.y, b0.z, b0.w};
      float By[4] = {b1.x, b1.y, b1.z, b1.w};
      float inter = inter_area_fast(Ax, Ay, Bx, By);
      float areaA = areaL[i];
      float areaB = areaL[j];
      float uni = (areaA + areaB) - inter;
      float iou = inter / fmaxf(uni, 1e-8f);
      if (iou > NMS_T)  // i == s (mod 8): local row (i-s)/8, word j>>6
        atomicOr(&lmask2[(((i - s) >> 3) << 3) | (j >> 6)], 1ull << (j & 63));
    }
  }
  __syncthreads();

  // ---- write own mask rows (plain coalesced store; rows >= V are zero) ----
  mask[((size_t)ci * NPROP + s + STRIPES * (tid >> 3)) * 8 + (tid & 7)] = lmask2[tid];
}

// ---------------- kernel 2: greedy NMS scan + last-block-per-image topk ----------------
// 30 blocks x 256 threads. Each block: NMS for its ci -> kkey; release fence;
// last-of-15 block per image acquires and runs the top-100 rank-select.
// Fence+election pattern correctness validated in R13 (absmax 0); here only
// 30 fences total (vs R13's 720) so the L2-writeback cost is ~1 us.
__global__ void __launch_bounds__(256) k_nmstk(
    const float* __restrict__ ssort, const u64* __restrict__ mask,
    const float* __restrict__ bsort,
    u64* __restrict__ kkey, int* __restrict__ done,
    float* __restrict__ out) {
  int ci = blockIdx.x;
  int b = ci / FG, cfg = ci - b * FG;
  __shared__ __align__(16) char arena[(NPROP + 4) * 8 * 8];  // 33 KB
  __shared__ u64 keptw[8];
  __shared__ int vcnt8[8];
  __shared__ int wpre[8];
  __shared__ int lastsh;
  int tid = threadIdx.x, lane = tid & 63, wv = tid >> 6;
  const float* ss = ssort + ci * NPROP;
  u64* lmask = (u64*)arena;
  // V via ballot popcount (ssort sorted desc => V = #valid) — no atomics
  for (int chunk = wv; chunk < 8; chunk += 4) {
    u64 bal = __ballot(ss[(chunk << 6) | lane] > SCORE_T);
    if (lane == 0) vcnt8[chunk] = (int)__popcll(bal);
  }
  __syncthreads();
  int V = 0;
#pragma unroll
  for (int w = 0; w < 8; ++w) V += vcnt8[w];
  for (int x = tid; x < V * 8; x += 256)
    lmask[x] = mask[(size_t)ci * NPROP * 8 + x];
  if (tid < 32) lmask[V * 8 + tid] = 0ull;  // pad rows V..V+3
  __syncthreads();
  if (tid == 0) {
    u64 rem[8] = {0, 0, 0, 0, 0, 0, 0, 0};
    u64 kept[8] = {0, 0, 0, 0, 0, 0, 0, 0};
    u64 buf[4][8];
#pragma unroll
    for (int d = 0; d < 4; ++d)
#pragma unroll
      for (int w = 0; w < 8; ++w) buf[d][w] = lmask[d * 8 + w];
    int kc = 0;
    bool stop = (V == 0);
#pragma unroll
    for (int w8 = 0; w8 < 8; ++w8) {
      int lim = V - (w8 << 6);
      lim = lim > 64 ? 64 : lim;
      if (!stop && lim > 0) {
        int lim4 = (lim + 3) & ~3;
        for (int bp4 = 0; bp4 < lim4 && !stop; bp4 += 4) {
#pragma unroll
          for (int d = 0; d < 4; ++d) {
            int bp = bp4 + d;
            int i = (w8 << 6) | bp;
            if (bp < lim && !stop) {
              if (!((rem[w8] >> bp) & 1ull)) {
                kept[w8] |= 1ull << bp;
#pragma unroll
                for (int w = 0; w < 8; ++w) rem[w] |= buf[d][w];
                if (++kc >= DETS) stop = true;  // first 100 kept determine output
              }
            }
#pragma unroll
            for (int w = 0; w < 8; ++w) buf[d][w] = lmask[(i + 4) * 8 + w];  // prefetch
          }
        }
      }
    }
#pragma unroll
    for (int w = 0; w < 8; ++w) keptw[w] = kept[w];
    int acc = 0;
#pragma unroll
    for (int w = 0; w < 8; ++w) { wpre[w] = acc; acc += (int)__popcll(keptw[w]); }
  }
  __syncthreads();
  for (int i = tid; i < NPROP; i += 256) {
    u64 kw = keptw[i >> 6];
    if ((kw >> (i & 63)) & 1ull) {
      int rank = wpre[i >> 6] + (int)__popcll(kw & ((1ull << (i & 63)) - 1ull));
      float s = ss[i];
      u32 hi = __float_as_uint(s) ^ 0x80000000u;  // s > 0.05 > 0
      u32 flat = (u32)(cfg * NPROP + i);
      kkey[ci * 128 + rank] = ((u64)hi << 32) | (u32)(~flat);  // ties: lower flat wins max
    }
  }
  int total = wpre[7] + (int)__popcll(keptw[7]);
  for (int r = tid; r < 128; r += 256)
    if (r >= total) kkey[ci * 128 + r] = 0ull;
  __syncthreads();

  // ---- release + last-of-15-classes election ----
  __threadfence();
  if (tid == 0) lastsh = atomicAdd(&done[b], 1);
  __syncthreads();
  if (lastsh != FG - 1) return;

  // ---- top-100 rank-select for this image (elected block) ----
  __threadfence();  // acquire: see all classes' kkey
  u64* lk = (u64*)arena;                       // 15360 B (reuse)
  u64* res = (u64*)(arena + FG * 128 * 8);     // 800 B
  __syncthreads();
  for (int x = tid; x < FG * 128; x += 256) lk[x] = kkey[b * FG * 128 + x];
  for (int x = tid; x < DETS; x += 256) res[x] = 0ull;
  __syncthreads();
  for (int x = tid; x < FG * 128; x += 256) {
    u64 key = lk[x];
    if (key == 0ull) continue;  // real keys have hi bit set (score > 0)
    int rank = 0;
#pragma unroll
    for (int cc = 0; cc < FG; ++cc) {
      const u64* a = &lk[cc * 128];
      int pos = 0;
#pragma unroll
      for (int st = 64; st > 0; st >>= 1)
        pos += (a[pos + st - 1] > key) ? st : 0;  // pos in [0,127]
      rank += pos + ((a[pos] > key) ? 1 : 0);
    }
    if (rank < DETS) res[rank] = key;
  }
  __syncthreads();
  if (tid < DETS) {
    u64 key = res[tid];
    float* o = out + ((size_t)b * DETS + tid) * 6;
    if (key == 0ull) {
#pragma unroll
      for (int q = 0; q < 6; ++q) o[q] = 0.f;
    } else {
      u32 flat = ~(u32)(key & 0xFFFFFFFFull);
      int cfg2 = flat >> 9, pos = flat & 511;
      const float* bx = bsort + (((size_t)b * FG + cfg2) * NPROP + pos) * 5;
#pragma unroll
      for (int q = 0; q < 5; ++q) o[q] = bx[q];
      o[5] = __uint_as_float((u32)(key >> 32) ^ 0x80000000u);
    }
  }
}

extern "C" void kernel_launch(void* const* d_in, const int* in_sizes, int n_in,
                              void* d_out, int out_size, void* d_ws, size_t ws_size,
                              hipStream_t stream) {
  const float* logits = (const float*)d_in[0];
  const float* regr   = (const float*)d_in[1];
  const float* prop   = (const float*)d_in[2];
  float* out = (float*)d_out;

  float* ssort = (float*)d_ws;                     // 15360 f
  float* bsort = ssort + NCI * NPROP;              // 76800 f
  u64* kkey    = (u64*)(bsort + NCI * NPROP * 5);  // 3840 u64 (368640 B offset, 8B-aligned)
  u64* mask    = kkey + NCI * 128;                 // 122880 u64
  int* done    = (int*)(mask + (size_t)NCI * NPROP * 8);  // 2 ints

  hipMemsetAsync(done, 0, 2 * sizeof(int), stream);  // graph-capture safe (R13-validated)
  hipLaunchKernelGGL(k_pipe, dim3(NCI, STRIPES), dim3(512), 0, stream,
                     logits, regr, prop, ssort, bsort, mask);
  hipLaunchKernelGGL(k_nmstk, dim3(NCI), dim3(256), 0, stream,
                     ssort, mask, bsort, kkey, done, out);
}

// Round 18
// 45.241 us; speedup vs baseline: 1.3235x; 1.3235x over previous
//
#include <hip/hip_runtime.h>

#define FG 15
#define NPROP 512
#define NCLS 16
#define NCI 30   // B*FG
#define SCORE_T 0.05f
#define NMS_T 0.5f
#define DETS 100
#define STRIPES 8
#define NWAVES 8
#define WCAP 512  // per-wave pair staging

typedef unsigned long long u64;
typedef unsigned int u32;

__device__ __forceinline__ unsigned sortable_f32(float f) {
  unsigned u = __float_as_uint(f);
  return u ^ ((u >> 31) ? 0xFFFFFFFFu : 0x80000000u);
}

// ---------------- register Sutherland-Hodgman (fast-math; IoU slack >> rounding) --------
#define CLIP_EMIT(V, VALIDEXPR, CX, CY, NX, NY)                                \
  {                                                                            \
    bool valid = (VALIDEXPR);                                                  \
    float cx = (CX), cy = (CY), nx = (NX), ny = (NY);                          \
    float sc = ex * (cy - p1y) - ey * (cx - p1x);                              \
    float sn = ex * (ny - p1y) - ey * (nx - p1x);                              \
    bool ic = sc >= 0.f, inn = sn >= 0.f;                                      \
    float den = sc - sn;                                                       \
    float dsel = (fabsf(den) > 1e-8f) ? den : 1.f;                             \
    float tt = sc * __builtin_amdgcn_rcpf(dsel);                               \
    float qx = cx + tt * (nx - cx);                                            \
    float qy = cy + tt * (ny - cy);                                            \
    bool fC = valid && ic;                                                     \
    bool fI = valid && (ic != inn);                                            \
    _Pragma("unroll") for (int o = 0; o < 8; ++o) if (o <= 2 * (V)) {          \
      bool wr = fC && (m == o);                                                \
      ox[o] = wr ? cx : ox[o];                                                 \
      oy[o] = wr ? cy : oy[o];                                                 \
    }                                                                          \
    m += fC ? 1 : 0;                                                           \
    _Pragma("unroll") for (int o = 0; o < 8; ++o) if (o <= 2 * (V) + 1) {      \
      bool wr = fI && (m == o);                                                \
      ox[o] = wr ? qx : ox[o];                                                 \
      oy[o] = wr ? qy : oy[o];                                                 \
    }                                                                          \
    m += fI ? 1 : 0;                                                           \
  }

__device__ __forceinline__ float inter_area_fast(const float (&Ax)[4], const float (&Ay)[4],
                                                 const float (&Bx)[4], const float (&By)[4]) {
  float inx[8], iny[8];
  int n = 4;
#pragma unroll
  for (int v = 0; v < 4; ++v) {
    inx[v] = Ax[v]; iny[v] = Ay[v];
    inx[v + 4] = 0.f; iny[v + 4] = 0.f;
  }
#pragma unroll
  for (int e = 0; e < 4; ++e) {
    int e2 = (e + 1) & 3;
    float p1x = Bx[e], p1y = By[e];
    float ex = Bx[e2] - p1x, ey = By[e2] - p1y;
    float ox[8], oy[8];
    int m = 0;
#pragma unroll
    for (int o = 0; o < 8; ++o) { ox[o] = 0.f; oy[o] = 0.f; }
    if (e == 0) {  // n == 4 statically
#pragma unroll
      for (int v = 0; v < 4; ++v) {
        CLIP_EMIT(v, true, inx[v], iny[v], inx[(v + 1) & 3], iny[(v + 1) & 3]);
      }
    } else {
#pragma unroll
      for (int v = 0; v < 8; ++v) {
        bool wrap = (v + 1 >= n);
        CLIP_EMIT(v, v < n, inx[v], iny[v],
                  wrap ? inx[0] : inx[(v + 1) & 7],
                  wrap ? iny[0] : iny[(v + 1) & 7]);
      }
    }
    n = (m < 8) ? m : 8;
#pragma unroll
    for (int o = 0; o < 8; ++o) { inx[o] = ox[o]; iny[o] = oy[o]; }
  }
  float s = 0.f;
#pragma unroll
  for (int v = 0; v < 8; ++v) {
    bool valid = v < n;
    bool wrap = (v + 1 >= n);
    float axx = inx[v], ayy = iny[v];
    float bxx = wrap ? inx[0] : inx[(v + 1) & 7];
    float byy = wrap ? iny[0] : iny[(v + 1) & 7];
    float cr = axx * byy - bxx * ayy;
    s += valid ? cr : 0.f;
  }
  float area = 0.5f * fabsf(s);
  return (n >= 3) ? area : 0.f;
}

// ---------------- kernel 1: decode + compacted rank-sort + AABB filter + clip ------------
// Block (ci,s) owns mask rows i == s (mod 8). Per-wave filter staging (no
// atomics), LDS-assembled mask written with plain coalesced stores. float4
// logits loads; fast __sinf/__cosf corners (decisions slack-protected);
// output boxes/scores bit-exact.
__global__ void __launch_bounds__(512) k_pipe(
    const float* __restrict__ logits, const float* __restrict__ regr,
    const float* __restrict__ prop,
    float* __restrict__ ssort, float* __restrict__ bsort,
    u64* __restrict__ mask) {
  int ci = blockIdx.x;
  int s = blockIdx.y;
  int b = ci / FG, c = ci - b * FG + 1;  // class 1..15
  int tid = threadIdx.x, lane = tid & 63, wv = tid >> 6;

  __shared__ __align__(16) u64 key2[NPROP + 8];     // compacted valid keys + pad
  __shared__ int rmap[NPROP];                       // orig tid -> rank
  __shared__ int cnt[NWAVES];
  __shared__ __align__(16) float crn[NPROP][8];     // 16 KB sorted corners
  __shared__ float4 aabb[NPROP];                    //  8 KB
  __shared__ float areaL[NPROP];                    //  2 KB
  __shared__ u32 stage[NWAVES][WCAP];               // 16 KB per-wave regions
  __shared__ int wcnts[NWAVES];
  __shared__ u64 lmask2[NPROP];                     //  4 KB own-rows mask

  lmask2[tid] = 0ull;

  // ---- decode + softmax (bit-identical to reference path) ----
  float sc, bb[5];
  u64 k;
  {
#pragma clang fp contract(off)
    int g = b * NPROP + tid;
    const float4* lg4 = (const float4*)(logits + g * NCLS);  // 64B-aligned
    float l[NCLS];
#pragma unroll
    for (int q4 = 0; q4 < 4; ++q4) {
      float4 v = lg4[q4];
      l[q4 * 4 + 0] = v.x; l[q4 * 4 + 1] = v.y;
      l[q4 * 4 + 2] = v.z; l[q4 * 4 + 3] = v.w;
    }
    float mx = -INFINITY;
#pragma unroll
    for (int q = 0; q < NCLS; ++q) mx = fmaxf(mx, l[q]);
    float sum = 0.f, ec = 0.f;
#pragma unroll
    for (int q = 0; q < NCLS; ++q) {
      float e = expf(l[q] - mx);
      sum += e;
      if (q == c) ec = e;
    }
    sc = ec / sum;
    const float* pb = prop + g * 5;
    float xc = pb[0], yc = pb[1], w = pb[2], h = pb[3], a = pb[4];
    const float* r = regr + g * 80 + c * 5;
    float dx = r[0] / 10.0f;
    float dy = r[1] / 10.0f;
    float dw = fminf(r[2] / 5.0f, 4.135166556742356f);
    float dh = fminf(r[3] / 5.0f, 4.135166556742356f);
    float da = r[4] / 10.0f;
    bb[0] = dx * w + xc;
    bb[1] = dy * h + yc;
    bb[2] = expf(dw) * w;
    bb[3] = expf(dh) * h;
    bb[4] = da * 57.29577951308232f + a;
    float m = (sc > SCORE_T) ? sc : -INFINITY;
    k = ((u64)(~sortable_f32(m)) << 32) | (u32)tid;  // asc key = desc score, asc idx
  }
  bool val = sc > SCORE_T;
  u64 bal = __ballot(val);
  if (lane == 0) cnt[wv] = (int)__popcll(bal);
  __syncthreads();
  int base = 0, V = 0;
#pragma unroll
  for (int w = 0; w < NWAVES; ++w) {
    int cw = cnt[w];
    base += (w < wv) ? cw : 0;
    V += cw;
  }
  if (val) key2[base + (int)__popcll(bal & ((1ull << lane) - 1ull))] = k;
  int Vpad = (V + 7) & ~7;
  if (tid < Vpad - V) key2[V + tid] = ~0ull;  // sentinel: > every real key
  __syncthreads();

  // ---- rank over valid-only keys (strictly distinct => bijective) ----
  if (tid < V) {
    u64 myk = key2[tid];
    int rank = 0;
    const ulonglong2* k2 = (const ulonglong2*)key2;
#pragma unroll 4
    for (int m = 0; m < Vpad / 2; ++m) {
      ulonglong2 kk = k2[m];  // ds_read_b128 broadcast
      rank += (kk.x < myk) ? 1 : 0;
      rank += (kk.y < myk) ? 1 : 0;
    }
    rmap[(int)(myk & 0xFFFFFFFFull)] = rank;
    if (s == 0) {  // bit-exact score recovery from the key
      u32 so = ~(u32)(myk >> 32);
      ssort[ci * NPROP + rank] = __uint_as_float(so ^ 0x80000000u);
    }
  }
  if (tid >= V && s == 0) ssort[ci * NPROP + tid] = -INFINITY;
  __syncthreads();

  // ---- scatter geometry by rank (fast trig; decisions slack-protected) ----
  if (val) {
    int r = rmap[tid];
    {
      float t = bb[4] * 0.017453292519943295f;
      float cs = __cosf(t), sn = __sinf(t);
      float hw = bb[2] * 0.5f, hh = bb[3] * 0.5f;
      float lx[4] = {-hw, hw, hw, -hw};
      float ly[4] = {-hh, -hh, hh, hh};
      float X[4], Y[4];
#pragma unroll
      for (int q = 0; q < 4; ++q) {
        X[q] = bb[0] + lx[q] * cs - ly[q] * sn;
        Y[q] = bb[1] + lx[q] * sn + ly[q] * cs;
      }
#pragma unroll
      for (int q = 0; q < 4; ++q) { crn[r][q] = X[q]; crn[r][4 + q] = Y[q]; }
      float xmn = fminf(fminf(X[0], X[1]), fminf(X[2], X[3]));
      float xmx = fmaxf(fmaxf(X[0], X[1]), fmaxf(X[2], X[3]));
      float ymn = fminf(fminf(Y[0], Y[1]), fminf(Y[2], Y[3]));
      float ymx = fmaxf(fmaxf(Y[0], Y[1]), fmaxf(Y[2], Y[3]));
      aabb[r] = make_float4(xmn, ymn, xmx, ymx);
      areaL[r] = bb[2] * bb[3];
      if (s == 0) {
        float* dst = bsort + ((size_t)ci * NPROP + r) * 5;
#pragma unroll
        for (int q = 0; q < 5; ++q) dst[q] = bb[q];
      }
    }
  }
  __syncthreads();

  // ---- phase 1: per-wave AABB filter, ballot-prefix staging (no atomics) ----
  // IoU>0.5 needs inter > (A+B)/3 and inter <= AABB-overlap-area, so require
  // AABBinter > 0.33*(A+B) (1% slack >> fp rounding; AABB-disjoint => inter==0).
  {
    int nch = (V + 63) >> 6;
    int wcnt = 0;
    for (int t = wv;; t += NWAVES) {
      int i = s + STRIPES * t;  // rows i == s (mod 8), round-robin over waves
      if (i >= V) break;
      float4 ai = aabb[i];
      float Ai = areaL[i];
      for (int ch = i >> 6; ch < nch; ++ch) {
        int j = (ch << 6) | lane;
        bool pass = false;
        if (j > i && j < V) {
          float4 aj = aabb[j];
          float ix = fminf(ai.z, aj.z) - fmaxf(ai.x, aj.x);
          float iy = fminf(ai.w, aj.w) - fmaxf(ai.y, aj.y);
          float ov = fmaxf(ix, 0.f) * fmaxf(iy, 0.f);  // >= exact quad intersection
          pass = ov > 0.33f * (Ai + areaL[j]);
        }
        u64 bal2 = __ballot(pass);
        if (pass) {
          int pos = wcnt + (int)__popcll(bal2 & ((1ull << lane) - 1ull));
          if (pos < WCAP) stage[wv][pos] = ((u32)i << 9) | (u32)j;
        }
        wcnt += (int)__popcll(bal2);
      }
    }
    if (lane == 0) wcnts[wv] = wcnt < WCAP ? wcnt : WCAP;
  }
  __syncthreads();

  // ---- phase 2: clip staged pairs (balanced over all 512 threads) ----
  {
    int c0 = wcnts[0], c1 = wcnts[1], c2 = wcnts[2], c3 = wcnts[3];
    int c4 = wcnts[4], c5 = wcnts[5], c6 = wcnts[6], c7 = wcnts[7];
    int p1 = c0, p2 = p1 + c1, p3 = p2 + c2, p4 = p3 + c3;
    int p5 = p4 + c4, p6 = p5 + c5, p7 = p6 + c6;
    int total = p7 + c7;
    for (int p = tid; p < total; p += 512) {
      int r = (p >= p1) + (p >= p2) + (p >= p3) + (p >= p4) +
              (p >= p5) + (p >= p6) + (p >= p7);
      u32 w = 0;
      switch (r) {  // static region indexing
        case 0: w = stage[0][p]; break;
        case 1: w = stage[1][p - p1]; break;
        case 2: w = stage[2][p - p2]; break;
        case 3: w = stage[3][p - p3]; break;
        case 4: w = stage[4][p - p4]; break;
        case 5: w = stage[5][p - p5]; break;
        case 6: w = stage[6][p - p6]; break;
        default: w = stage[7][p - p7]; break;
      }
      int i = w >> 9, j = w & 511;
      float4 a0 = *(const float4*)&crn[i][0];
      float4 a1 = *(const float4*)&crn[i][4];
      float4 b0 = *(const float4*)&crn[j][0];
      float4 b1 = *(const float4*)&crn[j][4];
      float Ax[4] = {a0.x, a0.y, a0.z, a0.w};
      float Ay[4] = {a1.x, a1.y, a1.z, a1.w};
      float Bx[4] = {b0.x, b0.y, b0.z, b0.w};
      float By[4] = {b1.x, b1.y, b1.z, b1.w};
      float inter = inter_area_fast(Ax, Ay, Bx, By);
      float areaA = areaL[i];
      float areaB = areaL[j];
      float uni = (areaA + areaB) - inter;
      float iou = inter / fmaxf(uni, 1e-8f);
      if (iou > NMS_T)  // i == s (mod 8): local row (i-s)/8, word j>>6
        atomicOr(&lmask2[(((i - s) >> 3) << 3) | (j >> 6)], 1ull << (j & 63));
    }
  }
  __syncthreads();

  // ---- write own mask rows (plain coalesced store; rows >= V are zero) ----
  mask[((size_t)ci * NPROP + s + STRIPES * (tid >> 3)) * 8 + (tid & 7)] = lmask2[tid];
}

// ---------------- kernel 2: greedy NMS scan (register-resident, prefetched) ----------------
__global__ void __launch_bounds__(256) k_nms(
    const float* __restrict__ ssort, const u64* __restrict__ mask,
    u64* __restrict__ kkey) {  // [NCI][128] sortable keys, desc, 0-filled
  int ci = blockIdx.x;
  int b = ci / FG, cfg = ci - b * FG;
  __shared__ u64 lmask[(NPROP + 4) * 8];  // 33 KB (+4 pad rows for prefetch)
  __shared__ u64 keptw[8];
  __shared__ int vcnt8[8];
  __shared__ int wpre[8];
  int tid = threadIdx.x, lane = tid & 63, wv = tid >> 6;
  const float* ss = ssort + ci * NPROP;
  // V via ballot popcount (ssort sorted desc => V = #valid) — no atomics
  for (int chunk = wv; chunk < 8; chunk += 4) {
    u64 bal = __ballot(ss[(chunk << 6) | lane] > SCORE_T);
    if (lane == 0) vcnt8[chunk] = (int)__popcll(bal);
  }
  __syncthreads();
  int V = 0;
#pragma unroll
  for (int w = 0; w < 8; ++w) V += vcnt8[w];
  for (int x = tid; x < V * 8; x += 256)
    lmask[x] = mask[(size_t)ci * NPROP * 8 + x];
  if (tid < 32) lmask[V * 8 + tid] = 0ull;  // pad rows V..V+3
  __syncthreads();
  if (tid == 0) {
    u64 rem[8] = {0, 0, 0, 0, 0, 0, 0, 0};
    u64 kept[8] = {0, 0, 0, 0, 0, 0, 0, 0};
    u64 buf[4][8];
#pragma unroll
    for (int d = 0; d < 4; ++d)
#pragma unroll
      for (int w = 0; w < 8; ++w) buf[d][w] = lmask[d * 8 + w];
    int kc = 0;
    bool stop = (V == 0);
#pragma unroll
    for (int w8 = 0; w8 < 8; ++w8) {
      int lim = V - (w8 << 6);
      lim = lim > 64 ? 64 : lim;
      if (!stop && lim > 0) {
        int lim4 = (lim + 3) & ~3;
        for (int bp4 = 0; bp4 < lim4 && !stop; bp4 += 4) {
#pragma unroll
          for (int d = 0; d < 4; ++d) {
            int bp = bp4 + d;
            int i = (w8 << 6) | bp;
            if (bp < lim && !stop) {
              if (!((rem[w8] >> bp) & 1ull)) {
                kept[w8] |= 1ull << bp;
#pragma unroll
                for (int w = 0; w < 8; ++w) rem[w] |= buf[d][w];
                if (++kc >= DETS) stop = true;  // first 100 kept determine output
              }
            }
#pragma unroll
            for (int w = 0; w < 8; ++w) buf[d][w] = lmask[(i + 4) * 8 + w];  // prefetch
          }
        }
      }
    }
#pragma unroll
    for (int w = 0; w < 8; ++w) keptw[w] = kept[w];
    int acc = 0;
#pragma unroll
    for (int w = 0; w < 8; ++w) { wpre[w] = acc; acc += (int)__popcll(keptw[w]); }
  }
  __syncthreads();
  for (int i = tid; i < NPROP; i += 256) {
    u64 kw = keptw[i >> 6];
    if ((kw >> (i & 63)) & 1ull) {
      int rank = wpre[i >> 6] + (int)__popcll(kw & ((1ull << (i & 63)) - 1ull));
      float s = ss[i];
      u32 hi = __float_as_uint(s) ^ 0x80000000u;  // s > 0.05 > 0
      u32 flat = (u32)(cfg * NPROP + i);
      kkey[ci * 128 + rank] = ((u64)hi << 32) | (u32)(~flat);  // ties: lower flat wins max
    }
  }
  int total = wpre[7] + (int)__popcll(keptw[7]);
  for (int r = tid; r < 128; r += 256)
    if (r >= total) kkey[ci * 128 + r] = 0ull;
}

// ---------------- kernel 3: parallel rank-select top-100 ----------------
__global__ void __launch_bounds__(1024) k_topk(
    const u64* __restrict__ kkey,
    const float* __restrict__ bsort,
    float* __restrict__ out) {
  int b = blockIdx.x;  // 2 blocks, 1024 threads
  __shared__ u64 lk[FG * 128];  // 15 KiB
  __shared__ u64 res[DETS];
  for (int x = threadIdx.x; x < FG * 128; x += 1024) lk[x] = kkey[b * FG * 128 + x];
  for (int x = threadIdx.x; x < DETS; x += 1024) res[x] = 0ull;
  __syncthreads();
  for (int x = threadIdx.x; x < FG * 128; x += 1024) {
    u64 key = lk[x];
    if (key == 0ull) continue;  // real keys have hi bit set (score > 0)
    int rank = 0;
#pragma unroll
    for (int c = 0; c < FG; ++c) {
      const u64* a = &lk[c * 128];
      int pos = 0;
#pragma unroll
      for (int st = 64; st > 0; st >>= 1)
        pos += (a[pos + st - 1] > key) ? st : 0;  // pos in [0,127]
      rank += pos + ((a[pos] > key) ? 1 : 0);
    }
    if (rank < DETS) res[rank] = key;
  }
  __syncthreads();
  if (threadIdx.x < DETS) {
    u64 key = res[threadIdx.x];
    float* o = out + ((size_t)b * DETS + threadIdx.x) * 6;
    if (key == 0ull) {
#pragma unroll
      for (int q = 0; q < 6; ++q) o[q] = 0.f;
    } else {
      u32 flat = ~(u32)(key & 0xFFFFFFFFull);
      int cfg = flat >> 9, pos = flat & 511;
      const float* bx = bsort + (((size_t)b * FG + cfg) * NPROP + pos) * 5;
#pragma unroll
      for (int q = 0; q < 5; ++q) o[q] = bx[q];
      o[5] = __uint_as_float((u32)(key >> 32) ^ 0x80000000u);
    }
  }
}

extern "C" void kernel_launch(void* const* d_in, const int* in_sizes, int n_in,
                              void* d_out, int out_size, void* d_ws, size_t ws_size,
                              hipStream_t stream) {
  const float* logits = (const float*)d_in[0];
  const float* regr   = (const float*)d_in[1];
  const float* prop   = (const float*)d_in[2];
  float* out = (float*)d_out;

  float* ssort = (float*)d_ws;                     // 15360 f
  float* bsort = ssort + NCI * NPROP;              // 76800 f
  u64* kkey    = (u64*)(bsort + NCI * NPROP * 5);  // 3840 u64 (368640 B offset, 8B-aligned)
  u64* mask    = kkey + NCI * 128;                 // 122880 u64 (~1.4 MB total)

  hipLaunchKernelGGL(k_pipe, dim3(NCI, STRIPES), dim3(512), 0, stream,
                     logits, regr, prop, ssort, bsort, mask);
  hipLaunchKernelGGL(k_nms, dim3(NCI), dim3(256), 0, stream, ssort, mask, kkey);
  hipLaunchKernelGGL(k_topk, dim3(2), dim3(1024), 0, stream, kkey, bsort, out);
}